// Round 4
// baseline (71.950 us; speedup 1.0000x reference)
//
#include <hip/hip_runtime.h>
#include <hip/hip_bf16.h>

#define DIM 8192

typedef __bf16 bf16x8 __attribute__((ext_vector_type(8)));
typedef __bf16 bf16x2 __attribute__((ext_vector_type(2)));
typedef float f32x4 __attribute__((ext_vector_type(4)));
typedef float f32x2 __attribute__((ext_vector_type(2)));

// fp32x4 -> bf16x4 (RNE via fptrunc -> packed v_cvt_pk_bf16_f32)
__device__ __forceinline__ uint2 cvt_f4(const float4 v) {
  bf16x2 lo = __builtin_convertvector((f32x2){v.x, v.y}, bf16x2);
  bf16x2 hi = __builtin_convertvector((f32x2){v.z, v.w}, bf16x2);
  uint2 r;
  r.x = __builtin_bit_cast(unsigned, lo);
  r.y = __builtin_bit_cast(unsigned, hi);
  return r;
}

// global->LDS direct DMA, 16B per lane. Global addr is PER-LANE (handles the
// circulant wrap); LDS base must be wave-uniform (no lane term).
#define GL2LDS(gp, lp)                                                        \
  __builtin_amdgcn_global_load_lds(                                           \
      (const __attribute__((address_space(1))) void*)(gp),                    \
      (__attribute__((address_space(3))) void*)(lp), 16, 0, 0)

// ---------------------------------------------------------------------------
// Prep: one-shot repack to bf16 in EXACTLY the LDS staging order, so phase 1
// can stage with pure global_load_lds (no per-WG cvt / bit-twiddle VALU).
//   X_prep [kc:16][s:16][b0:2][kh:4][p:16][j:8]  bf16  (512 KB in ws)
//   W_prep [d:512][qh:2][p:16][j:8]              bf16  (256 KB in ws)
// Also zeroes Out (phase 1 accumulates into it with atomics).
// Grid 256x256 = 65536 threads: 32768 X-chunks, 16384 Blk-chunks, 16384 zeroers.
// ---------------------------------------------------------------------------
__global__ __launch_bounds__(256)
void bcl_prep_kernel(const float* __restrict__ X, const float* __restrict__ Blk,
                     unsigned short* __restrict__ Xp, unsigned short* __restrict__ Wp,
                     float4* __restrict__ Out) {
  const int T = blockIdx.x * 256 + threadIdx.x;
  if (T < 32768) {                       // X chunk: 8 contiguous k's of one row
    const int c  = T;
    const int p  = c & 15;
    const int kh = (c >> 4) & 3;
    const int b0 = (c >> 6) & 1;
    const int s  = (c >> 7) & 15;
    const int kc = c >> 11;
    const float* src = X + (b0 * 16 + p) * DIM + kc * 512 + s * 32 +
                       ((kh >> 1) << 4) + ((kh & 1) << 3);
    const float4 v0 = reinterpret_cast<const float4*>(src)[0];
    const float4 v1 = reinterpret_cast<const float4*>(src)[1];
    const uint2 a = cvt_f4(v0), b = cvt_f4(v1);
    uint4 o; o.x = a.x; o.y = a.y; o.z = b.x; o.w = b.y;
    *reinterpret_cast<uint4*>(Xp + c * 8) = o;
  } else if (T < 49152) {                // Blk chunk: 8 contiguous q's
    const int b  = T - 32768;
    const int d  = b >> 5;
    const int q5 = b & 31;               // = qh*16 + p
    const int p  = q5 & 15;
    const int qh = q5 >> 4;
    const float* src = Blk + d * 256 + p * 16 + qh * 8;
    const float4 v0 = reinterpret_cast<const float4*>(src)[0];
    const float4 v1 = reinterpret_cast<const float4*>(src)[1];
    const uint2 a = cvt_f4(v0), bb = cvt_f4(v1);
    uint4 o; o.x = a.x; o.y = a.y; o.z = bb.x; o.w = bb.y;
    *reinterpret_cast<uint4*>(Wp + b * 8) = o;
  } else {                               // zero Out: 16 f32 each
    const int z = T - 49152;
    const float4 zero = {0.f, 0.f, 0.f, 0.f};
    #pragma unroll
    for (int i = 0; i < 4; ++i) Out[z * 4 + i] = zero;
  }
}

// ---------------------------------------------------------------------------
// Phase 1: grid 512 = 32 mc x 16 kc; block 512 (8 waves), 2 WG/CU (4 waves/EU).
// Staging is pure global_load_lds (7 wave-insts/thread, circulant wrap folded
// into the per-lane global address). Hot loop: 16x16x32 MFMA, both operand
// reads wave-contiguous 1KB ds_read_b128 (conflict-free; layout verified in
// earlier rounds). Epilogue: fp32 atomicAdd into Out (16 kc partials meet
// there) -- no 16MB partials round-trip, no reduce kernel.
// ---------------------------------------------------------------------------
__global__ __launch_bounds__(512, 4)
void bcl_mfma_kernel(const unsigned short* __restrict__ Xp,
                     const unsigned short* __restrict__ Wp,
                     float* __restrict__ Out) {
  // x: [s:16][b0:2][kh:4][p:16][j:8] bf16 (32 KB): frag = contiguous 1KB
  __shared__ __align__(16) unsigned short Xl[16384];
  // blocks window: 48 slots x 512B (slot 47 staged but never read)
  __shared__ __align__(16) unsigned short Wl[48 * 256];

  const int tid  = threadIdx.x;
  const int lane = tid & 63;
  const int wid  = tid >> 6;              // 0..7
  const int mc   = blockIdx.x & 31;
  const int kc   = blockIdx.x >> 5;

  // ---- stage X: 32 KB linear DMA (4 x 1KB wave-insts per wave)
  const char* xsrc = reinterpret_cast<const char*>(Xp + kc * 16384);
  #pragma unroll
  for (int ro = 0; ro < 4; ++ro) {
    const int lb = ro * 8192 + wid * 1024;          // uniform LDS byte base
    GL2LDS(xsrc + lb + lane * 16, reinterpret_cast<char*>(Xl) + lb);
  }

  // ---- stage blocks window: slot w holds blocks[(dbase+w)&511] repacked.
  // 24 KB = 3 x 1KB wave-insts per wave; wrap handled per-lane in gaddr.
  const int dbase = (mc * 16 - kc * 32 - 31) & 511;
  const char* wsrc = reinterpret_cast<const char*>(Wp);
  #pragma unroll
  for (int ro = 0; ro < 3; ++ro) {
    const int lb = ro * 8192 + wid * 1024;          // uniform LDS byte base
    const int B  = lb + lane * 16;                  // per-lane byte offset
    const int w  = B >> 9;                          // window slot
    const int d  = (dbase + w) & 511;               // circulant block index
    GL2LDS(wsrc + d * 512 + (B & 511), reinterpret_cast<char*>(Wl) + lb);
  }

  __syncthreads();   // drains vmcnt (global_load_lds) + barrier

  // x-frag (a-operand): lane l -> Xl[s*1024 + b0*512 + l*8]
  const unsigned short* Xb = &Xl[lane << 3];
  // blocks-frag (b-operand): lanes 0-31 read slot w0, 32-63 read slot w0-1,
  // each half contiguous 512B; flat = (w0-1)*256 elems + per-lane offset:
  const unsigned short* Wb = &Wl[(((lane >> 5) ^ 1) << 8) + (((lane >> 4) & 1) << 7) + ((lane & 15) << 3)];

  f32x4 acc[2][2];
  #pragma unroll
  for (int t = 0; t < 2; ++t)
    #pragma unroll
    for (int b = 0; b < 2; ++b)
      acc[t][b] = (f32x4){0.f, 0.f, 0.f, 0.f};

  #pragma unroll 4
  for (int s = 0; s < 16; ++s) {
    const bf16x8 x0 = *reinterpret_cast<const bf16x8*>(Xb + (s << 10));
    const bf16x8 x1 = *reinterpret_cast<const bf16x8*>(Xb + (s << 10) + 512);
    #pragma unroll
    for (int t = 0; t < 2; ++t) {
      const int mt = (wid << 1) + t;      // 0..15
      const bf16x8 wf = *reinterpret_cast<const bf16x8*>(Wb + ((mt + 30 - 2 * s) << 8));
      acc[t][0] = __builtin_amdgcn_mfma_f32_16x16x32_bf16(x0, wf, acc[t][0], 0, 0, 0);
      acc[t][1] = __builtin_amdgcn_mfma_f32_16x16x32_bf16(x1, wf, acc[t][1], 0, 0, 0);
    }
  }

  // ---- epilogue: C/D layout col=lane&15 (=p within tile), row=(lane>>4)*4+reg.
  // Direct fp32 atomic accumulate into Out (device-scope, fire-and-forget).
  float* outp = Out + mc * 256;
  #pragma unroll
  for (int t = 0; t < 2; ++t) {
    const int col = ((wid << 1) + t) * 16 + (lane & 15);
    #pragma unroll
    for (int b0 = 0; b0 < 2; ++b0) {
      const int brow = b0 * 16 + ((lane >> 4) << 2);
      #pragma unroll
      for (int r = 0; r < 4; ++r)
        atomicAdd(outp + (brow + r) * DIM + col, acc[t][b0][r]);
    }
  }
}

extern "C" void kernel_launch(void* const* d_in, const int* in_sizes, int n_in,
                              void* d_out, int out_size, void* d_ws, size_t ws_size,
                              hipStream_t stream) {
  const float* X   = (const float*)d_in[0];     // [32, 8192] fp32
  const float* Blk = (const float*)d_in[1];     // [512, 16, 16] fp32
  unsigned short* Xp = (unsigned short*)d_ws;   // 512 KB bf16 repack of X
  unsigned short* Wp = Xp + 262144;             // 256 KB bf16 repack of blocks
  float* Out = (float*)d_out;                   // [32, 8192] fp32

  bcl_prep_kernel<<<dim3(256), dim3(256), 0, stream>>>(X, Blk, Xp, Wp, (float4*)Out);
  bcl_mfma_kernel<<<dim3(512), dim3(512), 0, stream>>>(Xp, Wp, Out);
}